// Round 1
// baseline (7836.721 us; speedup 1.0000x reference)
//
#include <hip/hip_runtime.h>
#include <hip/hip_bf16.h>

// Problem constants (B=4, S=2048, D=1024, H=16, DK=64)
#define BB 4
#define SS 2048
#define DD 1024
#define HH 16
#define DKK 64

typedef __bf16 bf16x8 __attribute__((ext_vector_type(8)));
typedef float floatx4 __attribute__((ext_vector_type(4)));

__device__ __forceinline__ float b2f(unsigned short u) {
    union { unsigned int i; float f; } c;
    c.i = ((unsigned int)u) << 16;
    return c.f;
}
__device__ __forceinline__ unsigned short f2b(float f) {
    unsigned int i = __float_as_uint(f);
    unsigned int r = (i + 0x7FFFu + ((i >> 16) & 1u)) >> 16;  // RNE
    return (unsigned short)r;
}

// ---------------------------------------------------------------------------
// fp32 -> bf16 conversion, 4 elems/thread
// ---------------------------------------------------------------------------
__global__ void cvt_f32_bf16(const float* __restrict__ in,
                             unsigned short* __restrict__ out, int n4) {
    int i = blockIdx.x * blockDim.x + threadIdx.x;
    if (i >= n4) return;
    float4 v = ((const float4*)in)[i];
    ushort4 o;
    o.x = f2b(v.x); o.y = f2b(v.y); o.z = f2b(v.z); o.w = f2b(v.w);
    ((ushort4*)out)[i] = o;
}

// ---------------------------------------------------------------------------
// NT GEMM: C[m,n] = sum_k A[m,k] * B[n,k]
// A: MxK bf16 row-major, B: NxK bf16 row-major, C: MxN (bf16 or fp32).
// One 16x16 tile per wave, mfma_f32_16x16x32_bf16, fragments direct from
// global (verified layouts: A free idx m = lane&15, k = (lane>>4)*8 + j;
// B free idx n = lane&15 same k; D col = lane&15, row = (lane>>4)*4 + r).
// ---------------------------------------------------------------------------
template <typename CT>
__global__ void gemm_nt(const unsigned short* __restrict__ A,
                        const unsigned short* __restrict__ B,
                        CT* __restrict__ C, int M, int N, int K) {
    int wid  = (int)((blockIdx.x * blockDim.x + threadIdx.x) >> 6);
    int lane = threadIdx.x & 63;
    int tiles_n = N >> 4;
    int tm = wid / tiles_n;
    int tn = wid - tm * tiles_n;
    if (tm * 16 >= M) return;

    int fr = lane & 15;        // free index (row of A / row of B == col of C)
    int ko = (lane >> 4) * 8;  // k offset of this lane's 8-elem chunk

    const bf16x8* Ap = (const bf16x8*)(A + (size_t)(tm * 16 + fr) * K + ko);
    const bf16x8* Bp = (const bf16x8*)(B + (size_t)(tn * 16 + fr) * K + ko);

    floatx4 acc = {0.f, 0.f, 0.f, 0.f};
#pragma unroll 8
    for (int k = 0; k < K; k += 32) {
        bf16x8 av = *Ap;
        bf16x8 bv = *Bp;
        acc = __builtin_amdgcn_mfma_f32_16x16x32_bf16(av, bv, acc, 0, 0, 0);
        Ap += 4;  // 32 bf16 = 4 x bf16x8
        Bp += 4;
    }

    int row0 = tm * 16 + (lane >> 4) * 4;
    int col  = tn * 16 + fr;
#pragma unroll
    for (int r = 0; r < 4; ++r) {
        size_t idx = (size_t)(row0 + r) * N + col;
        if constexpr (sizeof(CT) == 2) {
            C[idx] = f2b(acc[r]);
        } else {
            C[idx] = acc[r];
        }
    }
}

// ---------------------------------------------------------------------------
// Causal flash attention. qkv: [B*S][3*D] bf16 (e = c*1024 + h*64 + dk).
// heads out: [B*S][D] bf16 (merged-head layout).
// One thread = one q row; 128 rows per block; K/V tiles of 32 staged in LDS
// as fp32. All lanes read identical LDS addresses in inner loops (broadcast).
// ---------------------------------------------------------------------------
#define QROWS 128
#define KT 32

__global__ __launch_bounds__(QROWS, 2) void attn_causal(
    const unsigned short* __restrict__ qkv,
    unsigned short* __restrict__ heads) {
    __shared__ float klds[KT][DKK];
    __shared__ float vlds[KT][DKK];

    int tid = threadIdx.x;
    int h = blockIdx.y, b = blockIdx.z;
    int q_idx = blockIdx.x * QROWS + tid;

    const unsigned short* qrow =
        qkv + (size_t)(b * SS + q_idx) * (3 * DD) + h * DKK;

    float q[DKK], o[DKK];
#pragma unroll
    for (int d = 0; d < DKK; ++d) {
        q[d] = b2f(qrow[d]);
        o[d] = 0.f;
    }

    float m = -1e30f, l = 0.f;
    int ntiles = ((blockIdx.x + 1) * QROWS) / KT;  // causal: only needed tiles

    for (int kt = 0; kt < ntiles; ++kt) {
        __syncthreads();
        // stage K and V tiles (bf16 -> fp32)
        for (int idx = tid; idx < KT * DKK; idx += QROWS) {
            int j = idx >> 6, d = idx & 63;
            size_t base = (size_t)(b * SS + kt * KT + j) * (3 * DD) + h * DKK + d;
            klds[j][d] = b2f(qkv[base + DD]);       // K at e-offset 1024
            vlds[j][d] = b2f(qkv[base + 2 * DD]);   // V at e-offset 2048
        }
        __syncthreads();

        // pass 1: scores + tile max
        float s[KT];
        float tmax = -1e30f;
#pragma unroll
        for (int j = 0; j < KT; ++j) {
            float acc = 0.f;
            const floatx4* kr = (const floatx4*)(&klds[j][0]);
#pragma unroll
            for (int d4 = 0; d4 < DKK / 4; ++d4) {
                floatx4 kk = kr[d4];
                acc += q[4 * d4 + 0] * kk[0] + q[4 * d4 + 1] * kk[1] +
                       q[4 * d4 + 2] * kk[2] + q[4 * d4 + 3] * kk[3];
            }
            acc *= 0.125f;  // 1/sqrt(64)
            int kpos = kt * KT + j;
            s[j] = (kpos <= q_idx) ? acc : -1e30f;
            tmax = fmaxf(tmax, s[j]);
        }

        // online softmax update
        float mnew = fmaxf(m, tmax);
        float alpha = __expf(m - mnew);
        float psum = 0.f;
#pragma unroll
        for (int j = 0; j < KT; ++j) {
            s[j] = __expf(s[j] - mnew);
            psum += s[j];
        }
        l = l * alpha + psum;
        m = mnew;
#pragma unroll
        for (int d = 0; d < DKK; ++d) o[d] *= alpha;

        // pass 2: O += P * V
#pragma unroll
        for (int j = 0; j < KT; ++j) {
            float pj = s[j];
            const floatx4* vr = (const floatx4*)(&vlds[j][0]);
#pragma unroll
            for (int d4 = 0; d4 < DKK / 4; ++d4) {
                floatx4 vv = vr[d4];
                o[4 * d4 + 0] += pj * vv[0];
                o[4 * d4 + 1] += pj * vv[1];
                o[4 * d4 + 2] += pj * vv[2];
                o[4 * d4 + 3] += pj * vv[3];
            }
        }
    }

    float inv_l = 1.f / l;
    unsigned short* orow = heads + (size_t)(b * SS + q_idx) * DD + h * DKK;
#pragma unroll
    for (int d = 0; d < DKK; ++d) orow[d] = f2b(o[d] * inv_l);
}

// ---------------------------------------------------------------------------
extern "C" void kernel_launch(void* const* d_in, const int* in_sizes, int n_in,
                              void* d_out, int out_size, void* d_ws,
                              size_t ws_size, hipStream_t stream) {
    const float* x    = (const float*)d_in[0];  // [B,S,D]    8388608
    const float* Wqkv = (const float*)d_in[1];  // [3D,D]     3145728
    const float* Wo   = (const float*)d_in[2];  // [D,D]      1048576
    float* out = (float*)d_out;                 // [B,S,D] fp32

    const size_t NX = (size_t)BB * SS * DD;       // 8388608
    const size_t NWQ = (size_t)3 * DD * DD;       // 3145728
    const size_t NWO = (size_t)DD * DD;           // 1048576

    unsigned short* xb     = (unsigned short*)d_ws;          // 16 MB
    unsigned short* wqkvb  = xb + NX;                        // 6 MB
    unsigned short* wob    = wqkvb + NWQ;                    // 2 MB
    unsigned short* qkvb   = wob + NWO;                      // [8192][3072] 48 MB
    unsigned short* headsb = qkvb + (size_t)BB * SS * 3 * DD;// [8192][1024] 16 MB
    // total ws use: ~92 MB

    // 1. fp32 -> bf16 conversions
    cvt_f32_bf16<<<(int)(NX / 4 / 256), 256, 0, stream>>>(x, xb, (int)(NX / 4));
    cvt_f32_bf16<<<(int)(NWQ / 4 / 256), 256, 0, stream>>>(Wqkv, wqkvb, (int)(NWQ / 4));
    cvt_f32_bf16<<<(int)(NWO / 4 / 256), 256, 0, stream>>>(Wo, wob, (int)(NWO / 4));

    // 2. QKV projection: [8192,1024] x [3072,1024]^T -> [8192,3072] bf16
    {
        int M = BB * SS, N = 3 * DD, K = DD;
        int waves = (M / 16) * (N / 16);
        gemm_nt<unsigned short><<<waves / 4, 256, 0, stream>>>(xb, wqkvb, qkvb, M, N, K);
    }

    // 3. causal attention -> merged heads [8192][1024] bf16
    attn_causal<<<dim3(SS / QROWS, HH, BB), QROWS, 0, stream>>>(qkvb, headsb);

    // 4. output projection: [8192,1024] x [1024,1024]^T -> [8192,1024] fp32
    {
        int M = BB * SS, N = DD, K = DD;
        int waves = (M / 16) * (N / 16);
        gemm_nt<float><<<waves / 4, 256, 0, stream>>>(headsb, wob, out, M, N, K);
    }
}

// Round 2
// 1289.506 us; speedup vs baseline: 6.0773x; 6.0773x over previous
//
#include <hip/hip_runtime.h>
#include <hip/hip_bf16.h>

// Problem constants (B=4, S=2048, D=1024, H=16, DK=64)
#define BB 4
#define SS 2048
#define DD 1024
#define HH 16
#define DKK 64

typedef __bf16 bf16x8 __attribute__((ext_vector_type(8)));
typedef float floatx4 __attribute__((ext_vector_type(4)));

__device__ __forceinline__ float b2f(unsigned short u) {
    union { unsigned int i; float f; } c;
    c.i = ((unsigned int)u) << 16;
    return c.f;
}
__device__ __forceinline__ unsigned short f2b(float f) {
    unsigned int i = __float_as_uint(f);
    unsigned int r = (i + 0x7FFFu + ((i >> 16) & 1u)) >> 16;  // RNE
    return (unsigned short)r;
}

// ---------------------------------------------------------------------------
// fp32 -> bf16 conversion, 4 elems/thread
// ---------------------------------------------------------------------------
__global__ void cvt_f32_bf16(const float* __restrict__ in,
                             unsigned short* __restrict__ out, int n4) {
    int i = blockIdx.x * blockDim.x + threadIdx.x;
    if (i >= n4) return;
    float4 v = ((const float4*)in)[i];
    ushort4 o;
    o.x = f2b(v.x); o.y = f2b(v.y); o.z = f2b(v.z); o.w = f2b(v.w);
    ((ushort4*)out)[i] = o;
}

// ---------------------------------------------------------------------------
// NT GEMM (unchanged from round 0): C[m,n] = sum_k A[m,k]*B[n,k]
// ---------------------------------------------------------------------------
template <typename CT>
__global__ void gemm_nt(const unsigned short* __restrict__ A,
                        const unsigned short* __restrict__ B,
                        CT* __restrict__ C, int M, int N, int K) {
    int wid  = (int)((blockIdx.x * blockDim.x + threadIdx.x) >> 6);
    int lane = threadIdx.x & 63;
    int tiles_n = N >> 4;
    int tm = wid / tiles_n;
    int tn = wid - tm * tiles_n;
    if (tm * 16 >= M) return;

    int fr = lane & 15;
    int ko = (lane >> 4) * 8;

    const bf16x8* Ap = (const bf16x8*)(A + (size_t)(tm * 16 + fr) * K + ko);
    const bf16x8* Bp = (const bf16x8*)(B + (size_t)(tn * 16 + fr) * K + ko);

    floatx4 acc = {0.f, 0.f, 0.f, 0.f};
#pragma unroll 8
    for (int k = 0; k < K; k += 32) {
        bf16x8 av = *Ap;
        bf16x8 bv = *Bp;
        acc = __builtin_amdgcn_mfma_f32_16x16x32_bf16(av, bv, acc, 0, 0, 0);
        Ap += 4;
        Bp += 4;
    }

    int row0 = tm * 16 + (lane >> 4) * 4;
    int col  = tn * 16 + fr;
#pragma unroll
    for (int r = 0; r < 4; ++r) {
        size_t idx = (size_t)(row0 + r) * N + col;
        if constexpr (sizeof(CT) == 2) {
            C[idx] = f2b(acc[r]);
        } else {
            C[idx] = acc[r];
        }
    }
}

// ---------------------------------------------------------------------------
// MFMA flash attention (causal). qkv: [B*S][3*D] bf16, heads: [B*S][D] bf16.
// Block = 256 threads = 4 waves; wave w owns q rows q0b+16w .. +15.
// KV tiles of BC=32 staged in LDS: K row-major [32][72] (pad->no conflicts,
// rows 144B = 16B aligned), V transposed [64][48] (rows 96B aligned).
// Verified fragment layouts (validated end-to-end by round-0 GEMM):
//   A: m=lane&15, k=(lane>>4)*8+j   C/D: col=lane&15, row=(lane>>4)*4+r
// Softmax lanes: row=lane&15, cols (lane>>4)*8..+7  == exactly this lane's
// PV A-fragment -> P packs straight into registers, no LDS round-trip.
// ---------------------------------------------------------------------------
#define BR 64   // q rows per block
#define BC 32   // kv cols per tile

__global__ __launch_bounds__(256, 4) void attn_mfma(
    const unsigned short* __restrict__ qkv,
    unsigned short* __restrict__ heads) {
    __shared__ unsigned short K_lds[BC][72];
    __shared__ unsigned short Vt_lds[DKK][48];
    __shared__ float S_lds[4][16][33];

    const int tid  = threadIdx.x;
    const int lane = tid & 63;
    const int w    = tid >> 6;
    const int h = blockIdx.y, b = blockIdx.z;
    const int q0b = blockIdx.x * BR;
    const int q0w = q0b + w * 16;

    const int row16 = lane & 15;   // A free index / C col / softmax row
    const int part  = lane >> 4;   // k-chunk index
    const int rbase = part * 4;    // C/D row base

    // Q fragments (persist across tiles): dk 0..31 and 32..63
    const unsigned short* qptr =
        qkv + (size_t)(b * SS + q0w + row16) * (3 * DD) + h * DKK;
    bf16x8 qf0 = *(const bf16x8*)(qptr + part * 8);
    bf16x8 qf1 = *(const bf16x8*)(qptr + 32 + part * 8);

    floatx4 O0 = {0,0,0,0}, O1 = {0,0,0,0}, O2 = {0,0,0,0}, O3 = {0,0,0,0};
    float m = -1e30f, l = 0.f;

    const int ntiles = (q0b + BR) / BC;
    const int srow = tid >> 3;    // staging: kv row 0..31
    const int schk = tid & 7;     // staging: dk chunk 0..7

    for (int t = 0; t < ntiles; ++t) {
        const int k0 = t * BC;
        __syncthreads();  // protect K/Vt/S from overwrite while in use
        {
            size_t gbase = (size_t)(b * SS + k0 + srow) * (3 * DD) +
                           DD + h * DKK + schk * 8;
            uint4 kv = *(const uint4*)(qkv + gbase);          // K row chunk
            *(uint4*)&K_lds[srow][schk * 8] = kv;
            uint4 vv = *(const uint4*)(qkv + gbase + DD);     // V row chunk
            unsigned short vs[8] = {
                (unsigned short)(vv.x & 0xffff), (unsigned short)(vv.x >> 16),
                (unsigned short)(vv.y & 0xffff), (unsigned short)(vv.y >> 16),
                (unsigned short)(vv.z & 0xffff), (unsigned short)(vv.z >> 16),
                (unsigned short)(vv.w & 0xffff), (unsigned short)(vv.w >> 16)};
#pragma unroll
            for (int j = 0; j < 8; ++j)
                Vt_lds[schk * 8 + j][srow] = vs[j];           // transpose
        }
        __syncthreads();

        const bool active = (k0 <= q0w + 15);
        if (active) {
            // ---- QK^T: S[16 q][32 k], two 16-col tiles ----
            floatx4 s0 = {0,0,0,0}, s1 = {0,0,0,0};
#pragma unroll
            for (int u = 0; u < 2; ++u) {
                bf16x8 qf = u ? qf1 : qf0;
                bf16x8 kf0 = *(const bf16x8*)&K_lds[row16][u * 32 + part * 8];
                bf16x8 kf1 = *(const bf16x8*)&K_lds[16 + row16][u * 32 + part * 8];
                s0 = __builtin_amdgcn_mfma_f32_16x16x32_bf16(qf, kf0, s0, 0, 0, 0);
                s1 = __builtin_amdgcn_mfma_f32_16x16x32_bf16(qf, kf1, s1, 0, 0, 0);
            }
            // mask + scale, write to S_lds (C layout -> row-major)
#pragma unroll
            for (int r = 0; r < 4; ++r) {
                int qa = q0w + rbase + r;
                int ka0 = k0 + row16, ka1 = k0 + 16 + row16;
                S_lds[w][rbase + r][row16]      = (ka0 <= qa) ? s0[r] * 0.125f : -1e30f;
                S_lds[w][rbase + r][16 + row16] = (ka1 <= qa) ? s1[r] * 0.125f : -1e30f;
            }
        }
        __syncthreads();
        if (active) {
            // ---- softmax: lane handles row=row16, cols part*8..+7 ----
            float sv[8];
            float mx = -1e30f;
#pragma unroll
            for (int j = 0; j < 8; ++j) {
                sv[j] = S_lds[w][row16][part * 8 + j];
                mx = fmaxf(mx, sv[j]);
            }
            mx = fmaxf(mx, __shfl_xor(mx, 16));
            mx = fmaxf(mx, __shfl_xor(mx, 32));
            float mnew = fmaxf(m, mx);
            float alpha = __expf(m - mnew);
            float ps = 0.f;
            unsigned short pu[8];
#pragma unroll
            for (int j = 0; j < 8; ++j) {
                float p = __expf(sv[j] - mnew);
                ps += p;
                pu[j] = f2b(p);
            }
            ps += __shfl_xor(ps, 16);
            ps += __shfl_xor(ps, 32);
            l = l * alpha + ps;
            m = mnew;
            union { unsigned short u[8]; bf16x8 v; } pp;
#pragma unroll
            for (int j = 0; j < 8; ++j) pp.u[j] = pu[j];

            // alpha for this lane's C rows (rbase..rbase+3), from softmax lanes
            float a0 = __shfl(alpha, rbase + 0);
            float a1 = __shfl(alpha, rbase + 1);
            float a2 = __shfl(alpha, rbase + 2);
            float a3 = __shfl(alpha, rbase + 3);
            O0[0] *= a0; O0[1] *= a1; O0[2] *= a2; O0[3] *= a3;
            O1[0] *= a0; O1[1] *= a1; O1[2] *= a2; O1[3] *= a3;
            O2[0] *= a0; O2[1] *= a1; O2[2] *= a2; O2[3] *= a3;
            O3[0] *= a0; O3[1] *= a1; O3[2] *= a2; O3[3] *= a3;

            // ---- PV: O[16 q][64 dk] += P[16][32] * V[32][64] ----
            bf16x8 vf0 = *(const bf16x8*)&Vt_lds[0  + row16][part * 8];
            bf16x8 vf1 = *(const bf16x8*)&Vt_lds[16 + row16][part * 8];
            bf16x8 vf2 = *(const bf16x8*)&Vt_lds[32 + row16][part * 8];
            bf16x8 vf3 = *(const bf16x8*)&Vt_lds[48 + row16][part * 8];
            O0 = __builtin_amdgcn_mfma_f32_16x16x32_bf16(pp.v, vf0, O0, 0, 0, 0);
            O1 = __builtin_amdgcn_mfma_f32_16x16x32_bf16(pp.v, vf1, O1, 0, 0, 0);
            O2 = __builtin_amdgcn_mfma_f32_16x16x32_bf16(pp.v, vf2, O2, 0, 0, 0);
            O3 = __builtin_amdgcn_mfma_f32_16x16x32_bf16(pp.v, vf3, O3, 0, 0, 0);
        }
    }

    // final normalize + write (C layout: row=rbase+r, col=n*16+row16)
    float li0 = 1.f / __shfl(l, rbase + 0);
    float li1 = 1.f / __shfl(l, rbase + 1);
    float li2 = 1.f / __shfl(l, rbase + 2);
    float li3 = 1.f / __shfl(l, rbase + 3);
    const floatx4 Os[4] = {O0, O1, O2, O3};
#pragma unroll
    for (int n = 0; n < 4; ++n) {
        floatx4 o = Os[n];
        int dk = n * 16 + row16;
        size_t base = (size_t)(b * SS + q0w + rbase) * DD + h * DKK + dk;
        heads[base]          = f2b(o[0] * li0);
        heads[base + DD]     = f2b(o[1] * li1);
        heads[base + 2 * DD] = f2b(o[2] * li2);
        heads[base + 3 * DD] = f2b(o[3] * li3);
    }
}

// ---------------------------------------------------------------------------
extern "C" void kernel_launch(void* const* d_in, const int* in_sizes, int n_in,
                              void* d_out, int out_size, void* d_ws,
                              size_t ws_size, hipStream_t stream) {
    const float* x    = (const float*)d_in[0];  // [B,S,D]
    const float* Wqkv = (const float*)d_in[1];  // [3D,D]
    const float* Wo   = (const float*)d_in[2];  // [D,D]
    float* out = (float*)d_out;                 // [B,S,D] fp32

    const size_t NX  = (size_t)BB * SS * DD;
    const size_t NWQ = (size_t)3 * DD * DD;
    const size_t NWO = (size_t)DD * DD;

    unsigned short* xb     = (unsigned short*)d_ws;
    unsigned short* wqkvb  = xb + NX;
    unsigned short* wob    = wqkvb + NWQ;
    unsigned short* qkvb   = wob + NWO;
    unsigned short* headsb = qkvb + (size_t)BB * SS * 3 * DD;

    cvt_f32_bf16<<<(int)(NX / 4 / 256), 256, 0, stream>>>(x, xb, (int)(NX / 4));
    cvt_f32_bf16<<<(int)(NWQ / 4 / 256), 256, 0, stream>>>(Wqkv, wqkvb, (int)(NWQ / 4));
    cvt_f32_bf16<<<(int)(NWO / 4 / 256), 256, 0, stream>>>(Wo, wob, (int)(NWO / 4));

    // QKV projection: [8192,1024] x [3072,1024]^T -> [8192,3072] bf16
    {
        int M = BB * SS, N = 3 * DD, K = DD;
        int waves = (M / 16) * (N / 16);
        gemm_nt<unsigned short><<<waves / 4, 256, 0, stream>>>(xb, wqkvb, qkvb, M, N, K);
    }

    // causal MFMA attention -> merged heads [8192][1024] bf16
    attn_mfma<<<dim3(SS / BR, HH, BB), 256, 0, stream>>>(qkvb, headsb);

    // output projection: [8192,1024] x [1024,1024]^T -> [8192,1024] fp32
    {
        int M = BB * SS, N = DD, K = DD;
        int waves = (M / 16) * (N / 16);
        gemm_nt<float><<<waves / 4, 256, 0, stream>>>(headsb, wob, out, M, N, K);
    }
}

// Round 3
// 467.544 us; speedup vs baseline: 16.7614x; 2.7580x over previous
//
#include <hip/hip_runtime.h>
#include <hip/hip_bf16.h>

// Problem constants (B=4, S=2048, D=1024, H=16, DK=64)
#define BB 4
#define SS 2048
#define DD 1024
#define HH 16
#define DKK 64

typedef __bf16 bf16x8 __attribute__((ext_vector_type(8)));
typedef float floatx4 __attribute__((ext_vector_type(4)));

__device__ __forceinline__ float b2f(unsigned short u) {
    union { unsigned int i; float f; } c;
    c.i = ((unsigned int)u) << 16;
    return c.f;
}
__device__ __forceinline__ unsigned short f2b(float f) {
    unsigned int i = __float_as_uint(f);
    unsigned int r = (i + 0x7FFFu + ((i >> 16) & 1u)) >> 16;  // RNE
    return (unsigned short)r;
}

// async global->LDS, 16 B per lane; LDS dst = wave-uniform base + lane*16
__device__ __forceinline__ void gload_lds16(const unsigned short* g,
                                            unsigned short* l) {
    __builtin_amdgcn_global_load_lds(
        (const __attribute__((address_space(1))) unsigned int*)g,
        (__attribute__((address_space(3))) unsigned int*)l, 16, 0, 0);
}

// ---------------------------------------------------------------------------
// fp32 -> bf16 conversion, 4 elems/thread
// ---------------------------------------------------------------------------
__global__ void cvt_f32_bf16(const float* __restrict__ in,
                             unsigned short* __restrict__ out, int n4) {
    int i = blockIdx.x * blockDim.x + threadIdx.x;
    if (i >= n4) return;
    float4 v = ((const float4*)in)[i];
    ushort4 o;
    o.x = f2b(v.x); o.y = f2b(v.y); o.z = f2b(v.z); o.w = f2b(v.w);
    ((ushort4*)out)[i] = o;
}

// ---------------------------------------------------------------------------
// m97-structure NT GEMM: C[m,n] = sum_k A[m,k]*B[n,k]
// A: MxK bf16 row-major, B: NxK bf16 row-major. 256 thr = 4 waves,
// 128x128 C-tile, BK=32. global_load_lds width-16 staging (LDS layout is
// exactly lane-ordered: lane i covers row base+ i/4, cols (i%4)*8..+7).
// Wave w -> 64x64 subtile at (wm,wn) = ((w&1)*64, (w>>1)*64); 4x4 MFMA accs.
// Fragment layouts (verified r0/r2): A m=lane&15, k=(lane>>4)*8+j;
// C/D col(2nd operand free idx)=lane&15, row=(lane>>4)*4+r.
// ---------------------------------------------------------------------------
template <typename CT>
__global__ void gemm_nt_lds(const unsigned short* __restrict__ A,
                            const unsigned short* __restrict__ B,
                            CT* __restrict__ C, int M, int N, int K) {
    __shared__ unsigned short Alds[128][32];  // 8 KB
    __shared__ unsigned short Blds[128][32];  // 8 KB

    const int tid  = threadIdx.x;
    const int lane = tid & 63;
    const int w    = tid >> 6;
    const int wm   = (w & 1) * 64;
    const int wn   = (w >> 1) * 64;

    const int m0 = blockIdx.x * 128;
    const int n0 = blockIdx.y * 128;

    const int row16 = lane & 15;
    const int part  = lane >> 4;
    const int rbase = part * 4;

    // staging coords: lane covers row (lane>>2), k-chunk (lane&3)*8
    const int srow = lane >> 2;
    const int scol = (lane & 3) * 8;

    const unsigned short* Ag = A + (size_t)(m0 + w * 16 + srow) * K + scol;
    const unsigned short* Bg = B + (size_t)(n0 + w * 16 + srow) * K + scol;
    unsigned short* Al = &Alds[w * 16][0];
    unsigned short* Bl = &Blds[w * 16][0];
    const size_t rstep = (size_t)64 * K;  // +64 rows

    floatx4 acc[4][4] = {};

    for (int k0 = 0; k0 < K; k0 += 32) {
        __syncthreads();
        gload_lds16(Ag + k0,         Al);
        gload_lds16(Ag + rstep + k0, Al + 64 * 32);
        gload_lds16(Bg + k0,         Bl);
        gload_lds16(Bg + rstep + k0, Bl + 64 * 32);
        __syncthreads();

        bf16x8 af[4], bf[4];
#pragma unroll
        for (int i = 0; i < 4; ++i)
            af[i] = *(const bf16x8*)&Alds[wm + i * 16 + row16][part * 8];
#pragma unroll
        for (int j = 0; j < 4; ++j)
            bf[j] = *(const bf16x8*)&Blds[wn + j * 16 + row16][part * 8];
#pragma unroll
        for (int i = 0; i < 4; ++i)
#pragma unroll
            for (int j = 0; j < 4; ++j)
                acc[i][j] = __builtin_amdgcn_mfma_f32_16x16x32_bf16(
                    af[i], bf[j], acc[i][j], 0, 0, 0);
    }

    // epilogue: C row = m0+wm+i*16+rbase+r, col = n0+wn+j*16+row16
#pragma unroll
    for (int i = 0; i < 4; ++i) {
#pragma unroll
        for (int j = 0; j < 4; ++j) {
            const int row = m0 + wm + i * 16 + rbase;
            const int col = n0 + wn + j * 16 + row16;
#pragma unroll
            for (int r = 0; r < 4; ++r) {
                size_t idx = (size_t)(row + r) * N + col;
                if constexpr (sizeof(CT) == 2) C[idx] = f2b(acc[i][j][r]);
                else                           C[idx] = acc[i][j][r];
            }
        }
    }
}

// ---------------------------------------------------------------------------
// MFMA flash attention (causal) — unchanged from round 2 (passing).
// ---------------------------------------------------------------------------
#define BR 64
#define BC 32

__global__ __launch_bounds__(256, 4) void attn_mfma(
    const unsigned short* __restrict__ qkv,
    unsigned short* __restrict__ heads) {
    __shared__ unsigned short K_lds[BC][72];
    __shared__ unsigned short Vt_lds[DKK][48];
    __shared__ float S_lds[4][16][33];

    const int tid  = threadIdx.x;
    const int lane = tid & 63;
    const int w    = tid >> 6;
    const int h = blockIdx.y, b = blockIdx.z;
    const int q0b = blockIdx.x * BR;
    const int q0w = q0b + w * 16;

    const int row16 = lane & 15;
    const int part  = lane >> 4;
    const int rbase = part * 4;

    const unsigned short* qptr =
        qkv + (size_t)(b * SS + q0w + row16) * (3 * DD) + h * DKK;
    bf16x8 qf0 = *(const bf16x8*)(qptr + part * 8);
    bf16x8 qf1 = *(const bf16x8*)(qptr + 32 + part * 8);

    floatx4 O0 = {0,0,0,0}, O1 = {0,0,0,0}, O2 = {0,0,0,0}, O3 = {0,0,0,0};
    float m = -1e30f, l = 0.f;

    const int ntiles = (q0b + BR) / BC;
    const int srow = tid >> 3;
    const int schk = tid & 7;

    for (int t = 0; t < ntiles; ++t) {
        const int k0 = t * BC;
        __syncthreads();
        {
            size_t gbase = (size_t)(b * SS + k0 + srow) * (3 * DD) +
                           DD + h * DKK + schk * 8;
            uint4 kv = *(const uint4*)(qkv + gbase);
            *(uint4*)&K_lds[srow][schk * 8] = kv;
            uint4 vv = *(const uint4*)(qkv + gbase + DD);
            unsigned short vs[8] = {
                (unsigned short)(vv.x & 0xffff), (unsigned short)(vv.x >> 16),
                (unsigned short)(vv.y & 0xffff), (unsigned short)(vv.y >> 16),
                (unsigned short)(vv.z & 0xffff), (unsigned short)(vv.z >> 16),
                (unsigned short)(vv.w & 0xffff), (unsigned short)(vv.w >> 16)};
#pragma unroll
            for (int j = 0; j < 8; ++j)
                Vt_lds[schk * 8 + j][srow] = vs[j];
        }
        __syncthreads();

        const bool active = (k0 <= q0w + 15);
        if (active) {
            floatx4 s0 = {0,0,0,0}, s1 = {0,0,0,0};
#pragma unroll
            for (int u = 0; u < 2; ++u) {
                bf16x8 qf = u ? qf1 : qf0;
                bf16x8 kf0 = *(const bf16x8*)&K_lds[row16][u * 32 + part * 8];
                bf16x8 kf1 = *(const bf16x8*)&K_lds[16 + row16][u * 32 + part * 8];
                s0 = __builtin_amdgcn_mfma_f32_16x16x32_bf16(qf, kf0, s0, 0, 0, 0);
                s1 = __builtin_amdgcn_mfma_f32_16x16x32_bf16(qf, kf1, s1, 0, 0, 0);
            }
#pragma unroll
            for (int r = 0; r < 4; ++r) {
                int qa = q0w + rbase + r;
                int ka0 = k0 + row16, ka1 = k0 + 16 + row16;
                S_lds[w][rbase + r][row16]      = (ka0 <= qa) ? s0[r] * 0.125f : -1e30f;
                S_lds[w][rbase + r][16 + row16] = (ka1 <= qa) ? s1[r] * 0.125f : -1e30f;
            }
        }
        __syncthreads();
        if (active) {
            float sv[8];
            float mx = -1e30f;
#pragma unroll
            for (int j = 0; j < 8; ++j) {
                sv[j] = S_lds[w][row16][part * 8 + j];
                mx = fmaxf(mx, sv[j]);
            }
            mx = fmaxf(mx, __shfl_xor(mx, 16));
            mx = fmaxf(mx, __shfl_xor(mx, 32));
            float mnew = fmaxf(m, mx);
            float alpha = __expf(m - mnew);
            float ps = 0.f;
            unsigned short pu[8];
#pragma unroll
            for (int j = 0; j < 8; ++j) {
                float p = __expf(sv[j] - mnew);
                ps += p;
                pu[j] = f2b(p);
            }
            ps += __shfl_xor(ps, 16);
            ps += __shfl_xor(ps, 32);
            l = l * alpha + ps;
            m = mnew;
            union { unsigned short u[8]; bf16x8 v; } pp;
#pragma unroll
            for (int j = 0; j < 8; ++j) pp.u[j] = pu[j];

            float a0 = __shfl(alpha, rbase + 0);
            float a1 = __shfl(alpha, rbase + 1);
            float a2 = __shfl(alpha, rbase + 2);
            float a3 = __shfl(alpha, rbase + 3);
            O0[0] *= a0; O0[1] *= a1; O0[2] *= a2; O0[3] *= a3;
            O1[0] *= a0; O1[1] *= a1; O1[2] *= a2; O1[3] *= a3;
            O2[0] *= a0; O2[1] *= a1; O2[2] *= a2; O2[3] *= a3;
            O3[0] *= a0; O3[1] *= a1; O3[2] *= a2; O3[3] *= a3;

            bf16x8 vf0 = *(const bf16x8*)&Vt_lds[0  + row16][part * 8];
            bf16x8 vf1 = *(const bf16x8*)&Vt_lds[16 + row16][part * 8];
            bf16x8 vf2 = *(const bf16x8*)&Vt_lds[32 + row16][part * 8];
            bf16x8 vf3 = *(const bf16x8*)&Vt_lds[48 + row16][part * 8];
            O0 = __builtin_amdgcn_mfma_f32_16x16x32_bf16(pp.v, vf0, O0, 0, 0, 0);
            O1 = __builtin_amdgcn_mfma_f32_16x16x32_bf16(pp.v, vf1, O1, 0, 0, 0);
            O2 = __builtin_amdgcn_mfma_f32_16x16x32_bf16(pp.v, vf2, O2, 0, 0, 0);
            O3 = __builtin_amdgcn_mfma_f32_16x16x32_bf16(pp.v, vf3, O3, 0, 0, 0);
        }
    }

    float li0 = 1.f / __shfl(l, rbase + 0);
    float li1 = 1.f / __shfl(l, rbase + 1);
    float li2 = 1.f / __shfl(l, rbase + 2);
    float li3 = 1.f / __shfl(l, rbase + 3);
    const floatx4 Os[4] = {O0, O1, O2, O3};
#pragma unroll
    for (int n = 0; n < 4; ++n) {
        floatx4 o = Os[n];
        int dk = n * 16 + row16;
        size_t base = (size_t)(b * SS + q0w + rbase) * DD + h * DKK + dk;
        heads[base]          = f2b(o[0] * li0);
        heads[base + DD]     = f2b(o[1] * li1);
        heads[base + 2 * DD] = f2b(o[2] * li2);
        heads[base + 3 * DD] = f2b(o[3] * li3);
    }
}

// ---------------------------------------------------------------------------
extern "C" void kernel_launch(void* const* d_in, const int* in_sizes, int n_in,
                              void* d_out, int out_size, void* d_ws,
                              size_t ws_size, hipStream_t stream) {
    const float* x    = (const float*)d_in[0];  // [B,S,D]
    const float* Wqkv = (const float*)d_in[1];  // [3D,D]
    const float* Wo   = (const float*)d_in[2];  // [D,D]
    float* out = (float*)d_out;                 // [B,S,D] fp32

    const size_t NX  = (size_t)BB * SS * DD;
    const size_t NWQ = (size_t)3 * DD * DD;
    const size_t NWO = (size_t)DD * DD;

    unsigned short* xb     = (unsigned short*)d_ws;
    unsigned short* wqkvb  = xb + NX;
    unsigned short* wob    = wqkvb + NWQ;
    unsigned short* qkvb   = wob + NWO;
    unsigned short* headsb = qkvb + (size_t)BB * SS * 3 * DD;

    cvt_f32_bf16<<<(int)(NX / 4 / 256), 256, 0, stream>>>(x, xb, (int)(NX / 4));
    cvt_f32_bf16<<<(int)(NWQ / 4 / 256), 256, 0, stream>>>(Wqkv, wqkvb, (int)(NWQ / 4));
    cvt_f32_bf16<<<(int)(NWO / 4 / 256), 256, 0, stream>>>(Wo, wob, (int)(NWO / 4));

    // QKV projection: [8192,1024] x [3072,1024]^T -> [8192,3072] bf16
    gemm_nt_lds<unsigned short><<<dim3(BB * SS / 128, 3 * DD / 128), 256, 0,
                                  stream>>>(xb, wqkvb, qkvb, BB * SS, 3 * DD, DD);

    // causal MFMA attention -> merged heads [8192][1024] bf16
    attn_mfma<<<dim3(SS / BR, HH, BB), 256, 0, stream>>>(qkvb, headsb);

    // output projection: [8192,1024] x [1024,1024]^T -> [8192,1024] fp32
    gemm_nt_lds<float><<<dim3(BB * SS / 128, DD / 128), 256, 0, stream>>>(
        headsb, wob, out, BB * SS, DD, DD);
}

// Round 4
// 364.576 us; speedup vs baseline: 21.4954x; 1.2824x over previous
//
#include <hip/hip_runtime.h>
#include <hip/hip_bf16.h>

// Problem constants (B=4, S=2048, D=1024, H=16, DK=64)
#define BB 4
#define SS 2048
#define DD 1024
#define HH 16
#define DKK 64

typedef __bf16 bf16x8 __attribute__((ext_vector_type(8)));
typedef float floatx4 __attribute__((ext_vector_type(4)));

__device__ __forceinline__ float b2f(unsigned short u) {
    union { unsigned int i; float f; } c;
    c.i = ((unsigned int)u) << 16;
    return c.f;
}
__device__ __forceinline__ unsigned short f2b(float f) {
    unsigned int i = __float_as_uint(f);
    unsigned int r = (i + 0x7FFFu + ((i >> 16) & 1u)) >> 16;  // RNE
    return (unsigned short)r;
}

// async global->LDS, 16 B per lane; LDS dst = wave-uniform base + lane*16
__device__ __forceinline__ void gload_lds16(const unsigned short* g,
                                            unsigned short* l) {
    __builtin_amdgcn_global_load_lds(
        (const __attribute__((address_space(1))) unsigned int*)g,
        (__attribute__((address_space(3))) unsigned int*)l, 16, 0, 0);
}

// ---------------------------------------------------------------------------
// fp32 -> bf16 conversion, 4 elems/thread
// ---------------------------------------------------------------------------
__global__ void cvt_f32_bf16(const float* __restrict__ in,
                             unsigned short* __restrict__ out, int n4) {
    int i = blockIdx.x * blockDim.x + threadIdx.x;
    if (i >= n4) return;
    float4 v = ((const float4*)in)[i];
    ushort4 o;
    o.x = f2b(v.x); o.y = f2b(v.y); o.z = f2b(v.z); o.w = f2b(v.w);
    ((ushort4*)out)[i] = o;
}

// ---------------------------------------------------------------------------
// m97-structure NT GEMM (unchanged from round 3).
// ---------------------------------------------------------------------------
template <typename CT>
__global__ void gemm_nt_lds(const unsigned short* __restrict__ A,
                            const unsigned short* __restrict__ B,
                            CT* __restrict__ C, int M, int N, int K) {
    __shared__ unsigned short Alds[128][32];
    __shared__ unsigned short Blds[128][32];

    const int tid  = threadIdx.x;
    const int lane = tid & 63;
    const int w    = tid >> 6;
    const int wm   = (w & 1) * 64;
    const int wn   = (w >> 1) * 64;

    const int m0 = blockIdx.x * 128;
    const int n0 = blockIdx.y * 128;

    const int row16 = lane & 15;
    const int part  = lane >> 4;
    const int rbase = part * 4;

    const int srow = lane >> 2;
    const int scol = (lane & 3) * 8;

    const unsigned short* Ag = A + (size_t)(m0 + w * 16 + srow) * K + scol;
    const unsigned short* Bg = B + (size_t)(n0 + w * 16 + srow) * K + scol;
    unsigned short* Al = &Alds[w * 16][0];
    unsigned short* Bl = &Blds[w * 16][0];
    const size_t rstep = (size_t)64 * K;

    floatx4 acc[4][4] = {};

    for (int k0 = 0; k0 < K; k0 += 32) {
        __syncthreads();
        gload_lds16(Ag + k0,         Al);
        gload_lds16(Ag + rstep + k0, Al + 64 * 32);
        gload_lds16(Bg + k0,         Bl);
        gload_lds16(Bg + rstep + k0, Bl + 64 * 32);
        __syncthreads();

        bf16x8 af[4], bfr[4];
#pragma unroll
        for (int i = 0; i < 4; ++i)
            af[i] = *(const bf16x8*)&Alds[wm + i * 16 + row16][part * 8];
#pragma unroll
        for (int j = 0; j < 4; ++j)
            bfr[j] = *(const bf16x8*)&Blds[wn + j * 16 + row16][part * 8];
#pragma unroll
        for (int i = 0; i < 4; ++i)
#pragma unroll
            for (int j = 0; j < 4; ++j)
                acc[i][j] = __builtin_amdgcn_mfma_f32_16x16x32_bf16(
                    af[i], bfr[j], acc[i][j], 0, 0, 0);
    }

#pragma unroll
    for (int i = 0; i < 4; ++i) {
#pragma unroll
        for (int j = 0; j < 4; ++j) {
            const int row = m0 + wm + i * 16 + rbase;
            const int col = n0 + wn + j * 16 + row16;
#pragma unroll
            for (int r = 0; r < 4; ++r) {
                size_t idx = (size_t)(row + r) * N + col;
                if constexpr (sizeof(CT) == 2) C[idx] = f2b(acc[i][j][r]);
                else                           C[idx] = acc[i][j][r];
            }
        }
    }
}

// ---------------------------------------------------------------------------
// repack_kv: per (b,h,stile of 64): build lane-linear MFMA-ready tiles.
//  Kp tile [2 (dk32-chunk)][64 s][32 dk]  : Kp[...] = K[s][dk]
//  Vt tile [2 (s32-chunk)][64 dk][32 s]   : Vt[...] = V[s][dk] transposed
// Tile = 4096 ushorts = 8 KB. Transpose via padded LDS (done ONCE here,
// instead of 16-way-conflict scalar writes per attention tile).
// ---------------------------------------------------------------------------
__global__ void repack_kv(const unsigned short* __restrict__ qkv,
                          unsigned short* __restrict__ Kp,
                          unsigned short* __restrict__ Vt) {
    __shared__ unsigned short Vs[64][72];  // pad 72 (144 B rows, 16B aligned)
    const int st = blockIdx.x, h = blockIdx.y, b = blockIdx.z;
    const int tid = threadIdx.x;
    const size_t base = ((size_t)((b * HH + h) * (SS / 64) + st)) * 4096;

#pragma unroll
    for (int p = 0; p < 2; ++p) {
        const int row = p * 32 + (tid >> 3);   // s within tile
        const int chunk = tid & 7;             // 8-elem dk chunk
        size_t src = (size_t)(b * SS + st * 64 + row) * (3 * DD) +
                     DD + h * DKK + chunk * 8;
        // K: straight chunked copy
        uint4 kv = *(const uint4*)(qkv + src);
        *(uint4*)(Kp + base + (chunk >> 2) * 2048 + row * 32 + (chunk & 3) * 8) = kv;
        // V: stage to LDS for transpose
        uint4 vv = *(const uint4*)(qkv + src + DD);
        *(uint4*)&Vs[row][chunk * 8] = vv;
    }
    __syncthreads();
#pragma unroll
    for (int p = 0; p < 2; ++p) {
        const int dk = p * 32 + (tid >> 3);
        const int s8 = tid & 7;                // 8-elem s chunk
        union { unsigned short u[8]; uint4 v; } pk;
#pragma unroll
        for (int j = 0; j < 8; ++j) pk.u[j] = Vs[s8 * 8 + j][dk];
        *(uint4*)(Vt + base + (s8 >> 2) * 2048 + dk * 32 + (s8 & 3) * 8) = pk.v;
    }
}

// ---------------------------------------------------------------------------
// MFMA flash attention v2 (causal). BR=128 q rows/block (4 waves x 32),
// BC=64 kv/tile. K & V^T staged via global_load_lds from pre-packed tiles
// (lane-linear copy, zero conflicts). 32 MFMAs per wave-tile.
// Fragment layouts (verified): A m=lane&15, k=(lane>>4)*8+j;
//                              C/D col=lane&15, row=(lane>>4)*4+r.
// ---------------------------------------------------------------------------
#define ABR 128
#define ABC 64

__global__ __launch_bounds__(256) void attn_mfma2(
    const unsigned short* __restrict__ qkv,
    const unsigned short* __restrict__ Kp,
    const unsigned short* __restrict__ Vt,
    unsigned short* __restrict__ heads) {
    __shared__ unsigned short Kl[4096];   // [2 dk-chunk][64 s][32 dk]
    __shared__ unsigned short Vtl[4096];  // [2 s-chunk][64 dk][32 s]
    __shared__ float Sl[4][32][68];       // per-wave scores, pad 68

    const int tid  = threadIdx.x;
    const int lane = tid & 63;
    const int w    = tid >> 6;
    const int h = blockIdx.y, b = blockIdx.z;
    const int bx = gridDim.x - 1 - blockIdx.x;  // hardest blocks first
    const int q0b = bx * ABR;
    const int q0w = q0b + w * 32;

    const int row16 = lane & 15;
    const int part  = lane >> 4;
    const int rbase = part * 4;

    // Q fragments: qf[qt][u] covers rows q0w+qt*16, dk chunk u
    bf16x8 qf[2][2];
#pragma unroll
    for (int qt = 0; qt < 2; ++qt)
#pragma unroll
        for (int u = 0; u < 2; ++u)
            qf[qt][u] = *(const bf16x8*)(qkv +
                (size_t)(b * SS + q0w + qt * 16 + row16) * (3 * DD) +
                h * DKK + u * 32 + part * 8);

    floatx4 O[2][4] = {};
    float mrow[2] = {-1e30f, -1e30f}, lrow[2] = {0.f, 0.f};

    const int ntiles = (q0b + ABR) / ABC;
    const size_t tb = ((size_t)(b * HH + h) * (SS / 64)) * 4096;

    for (int t = 0; t < ntiles; ++t) {
        const int k0 = t * ABC;
        __syncthreads();
        {
            const unsigned short* ks = Kp + tb + (size_t)t * 4096 + w * 1024 + lane * 8;
            const unsigned short* vs = Vt + tb + (size_t)t * 4096 + w * 1024 + lane * 8;
            gload_lds16(ks,       Kl + w * 1024);
            gload_lds16(ks + 512, Kl + w * 1024 + 512);
            gload_lds16(vs,       Vtl + w * 1024);
            gload_lds16(vs + 512, Vtl + w * 1024 + 512);
        }
        __syncthreads();

        if (k0 <= q0w + 31) {
            // ---- QK^T: sc[qt][kt] over 64 k-cols ----
            floatx4 sc[2][4] = {};
#pragma unroll
            for (int u = 0; u < 2; ++u)
#pragma unroll
                for (int kt = 0; kt < 4; ++kt) {
                    bf16x8 kf = *(const bf16x8*)&Kl[u * 2048 +
                        (kt * 16 + row16) * 32 + part * 8];
                    sc[0][kt] = __builtin_amdgcn_mfma_f32_16x16x32_bf16(
                        qf[0][u], kf, sc[0][kt], 0, 0, 0);
                    sc[1][kt] = __builtin_amdgcn_mfma_f32_16x16x32_bf16(
                        qf[1][u], kf, sc[1][kt], 0, 0, 0);
                }
            // mask + scale -> Sl (C layout -> row-major; 2-way banks = free)
#pragma unroll
            for (int qt = 0; qt < 2; ++qt)
#pragma unroll
                for (int kt = 0; kt < 4; ++kt) {
                    int ka = k0 + kt * 16 + row16;
#pragma unroll
                    for (int r = 0; r < 4; ++r) {
                        int qa = q0w + qt * 16 + rbase + r;
                        Sl[w][qt * 16 + rbase + r][kt * 16 + row16] =
                            (ka <= qa) ? sc[qt][kt][r] * 0.125f : -1e30f;
                    }
                }
            // per-wave partition -> no cross-wave sync needed
#pragma unroll
            for (int qt = 0; qt < 2; ++qt) {
                // softmax: lane owns row=row16, cols {u*32+part*8..+7}
                const floatx4* sp = (const floatx4*)&Sl[w][qt * 16 + row16][0];
                floatx4 v0 = sp[part * 2];
                floatx4 v1 = sp[part * 2 + 1];
                floatx4 v2 = sp[8 + part * 2];
                floatx4 v3 = sp[8 + part * 2 + 1];
                float mx = -1e30f;
#pragma unroll
                for (int j = 0; j < 4; ++j) {
                    mx = fmaxf(mx, fmaxf(fmaxf(v0[j], v1[j]), fmaxf(v2[j], v3[j])));
                }
                mx = fmaxf(mx, __shfl_xor(mx, 16));
                mx = fmaxf(mx, __shfl_xor(mx, 32));
                float mnew = fmaxf(mrow[qt], mx);
                float alpha = __expf(mrow[qt] - mnew);
                union { unsigned short u[8]; bf16x8 v; } p0, p1;
                float ps = 0.f;
#pragma unroll
                for (int j = 0; j < 4; ++j) {
                    float e0 = __expf(v0[j] - mnew);
                    float e1 = __expf(v1[j] - mnew);
                    float e2 = __expf(v2[j] - mnew);
                    float e3 = __expf(v3[j] - mnew);
                    ps += (e0 + e1) + (e2 + e3);
                    p0.u[j] = f2b(e0); p0.u[4 + j] = f2b(e1);
                    p1.u[j] = f2b(e2); p1.u[4 + j] = f2b(e3);
                }
                ps += __shfl_xor(ps, 16);
                ps += __shfl_xor(ps, 32);
                lrow[qt] = lrow[qt] * alpha + ps;
                mrow[qt] = mnew;

                float a0 = __shfl(alpha, rbase + 0);
                float a1 = __shfl(alpha, rbase + 1);
                float a2 = __shfl(alpha, rbase + 2);
                float a3 = __shfl(alpha, rbase + 3);
#pragma unroll
                for (int dt = 0; dt < 4; ++dt) {
                    O[qt][dt][0] *= a0; O[qt][dt][1] *= a1;
                    O[qt][dt][2] *= a2; O[qt][dt][3] *= a3;
                }
                // PV: O[qt][dt] += P * V
#pragma unroll
                for (int u = 0; u < 2; ++u) {
                    bf16x8 pv = u ? p1.v : p0.v;
#pragma unroll
                    for (int dt = 0; dt < 4; ++dt) {
                        bf16x8 vf = *(const bf16x8*)&Vtl[u * 2048 +
                            (dt * 16 + row16) * 32 + part * 8];
                        O[qt][dt] = __builtin_amdgcn_mfma_f32_16x16x32_bf16(
                            pv, vf, O[qt][dt], 0, 0, 0);
                    }
                }
            }
        }
    }

    // epilogue: normalize + store merged-head bf16
#pragma unroll
    for (int qt = 0; qt < 2; ++qt) {
        float li0 = 1.f / __shfl(lrow[qt], rbase + 0);
        float li1 = 1.f / __shfl(lrow[qt], rbase + 1);
        float li2 = 1.f / __shfl(lrow[qt], rbase + 2);
        float li3 = 1.f / __shfl(lrow[qt], rbase + 3);
#pragma unroll
        for (int dt = 0; dt < 4; ++dt) {
            int dk = dt * 16 + row16;
            size_t base = (size_t)(b * SS + q0w + qt * 16 + rbase) * DD +
                          h * DKK + dk;
            heads[base]          = f2b(O[qt][dt][0] * li0);
            heads[base + DD]     = f2b(O[qt][dt][1] * li1);
            heads[base + 2 * DD] = f2b(O[qt][dt][2] * li2);
            heads[base + 3 * DD] = f2b(O[qt][dt][3] * li3);
        }
    }
}

// ---------------------------------------------------------------------------
extern "C" void kernel_launch(void* const* d_in, const int* in_sizes, int n_in,
                              void* d_out, int out_size, void* d_ws,
                              size_t ws_size, hipStream_t stream) {
    const float* x    = (const float*)d_in[0];
    const float* Wqkv = (const float*)d_in[1];
    const float* Wo   = (const float*)d_in[2];
    float* out = (float*)d_out;

    const size_t NX  = (size_t)BB * SS * DD;
    const size_t NWQ = (size_t)3 * DD * DD;
    const size_t NWO = (size_t)DD * DD;
    const size_t NKV = (size_t)BB * HH * SS * DKK;  // 8.39M elems

    unsigned short* xb     = (unsigned short*)d_ws;
    unsigned short* wqkvb  = xb + NX;
    unsigned short* wob    = wqkvb + NWQ;
    unsigned short* qkvb   = wob + NWO;
    unsigned short* headsb = qkvb + (size_t)BB * SS * 3 * DD;
    unsigned short* Kp     = headsb + NX;
    unsigned short* Vtp    = Kp + NKV;
    // total ws use: ~126 MB

    cvt_f32_bf16<<<(int)(NX / 4 / 256), 256, 0, stream>>>(x, xb, (int)(NX / 4));
    cvt_f32_bf16<<<(int)(NWQ / 4 / 256), 256, 0, stream>>>(Wqkv, wqkvb, (int)(NWQ / 4));
    cvt_f32_bf16<<<(int)(NWO / 4 / 256), 256, 0, stream>>>(Wo, wob, (int)(NWO / 4));

    // QKV projection
    gemm_nt_lds<unsigned short><<<dim3(BB * SS / 128, 3 * DD / 128), 256, 0,
                                  stream>>>(xb, wqkvb, qkvb, BB * SS, 3 * DD, DD);

    // repack K/V into MFMA-ready lane-linear tiles
    repack_kv<<<dim3(SS / 64, HH, BB), 256, 0, stream>>>(qkvb, Kp, Vtp);

    // causal MFMA attention
    attn_mfma2<<<dim3(SS / ABR, HH, BB), 256, 0, stream>>>(qkvb, Kp, Vtp, headsb);

    // output projection
    gemm_nt_lds<float><<<dim3(BB * SS / 128, DD / 128), 256, 0, stream>>>(
        headsb, wob, out, BB * SS, DD, DD);
}